// Round 13
// baseline (29.425 us; speedup 1.0000x reference)
//
#include <hip/hip_runtime.h>

// Problem constants (fixed by reference setup_inputs): D=32 detectors,
// in_s = out_s = 64, row stride 2048 floats, B = 8192.
#define NDET    32
#define SEG     64
#define ROWLEN  2048
#define TILE_B  256
#define THREADS 512
#define XSTR    72   // x LDS row stride, bf16 (144B, 16B-aligned, padded)
#define WSTR    72   // W LDS row stride, bf16
#define YSTR    68   // y LDS row stride, f32 (272B, 16B-aligned, padded)

typedef __bf16 bf16x8 __attribute__((ext_vector_type(8)));
typedef __bf16 bf16x4 __attribute__((ext_vector_type(4)));
typedef float  f32x4  __attribute__((ext_vector_type(4)));

__device__ __forceinline__ bf16x4 cvt4(f32x4 a) {
  bf16x4 r;
  r[0] = (__bf16)a[0]; r[1] = (__bf16)a[1]; r[2] = (__bf16)a[2]; r[3] = (__bf16)a[3];
  return r;
}

// y[b, d*64+o] = sum_i x[b, d*64+i] * W[d*64+o, d*64+i]
//
// v13 = v12 (best: coalesced staging + LDS output transpose + nt stores)
// scaled to TILE_B=256 with 8 waves: W staged ONCE per 256 rows instead of
// 128 -> W fabric traffic halves (32->16 MB of the ~160 MB total). All
// per-byte access patterns identical to v12. LDS union 69.6 KB -> 2
// blocks/CU (known-OK from v10).
__global__ __launch_bounds__(THREADS) void ensemble_linear_v13(
    const float* __restrict__ x, const float* __restrict__ W,
    float* __restrict__ y) {
  const int d     = blockIdx.y;
  const int b0    = blockIdx.x * TILE_B;
  const int t     = threadIdx.x;
  const int lane  = t & 63;
  const int wid   = t >> 6;        // 0..7
  const int dbase = d * SEG;

  const int rq  = lane >> 4;       // staging: row within 4-row quad
  const int c4  = lane & 15;       // staging: 16B chunk within 256B row
  const int m16 = lane & 15;       // fragment M/N index
  const int kg  = lane >> 4;       // fragment k-group

  // Phase A: xls [256][XSTR] bf16 (36864B) + wls [64][WSTR] bf16 (9216B)
  // Phase B: yls [256][YSTR] f32 (69632B) overlaid.
  __shared__ __align__(16) unsigned char smem[TILE_B * YSTR * 4];  // 69632B
  __bf16* xls = (__bf16*)smem;                        // [256][XSTR]
  __bf16* wls = (__bf16*)(smem + TILE_B * XSTR * 2);  // [64][WSTR]
  float*  yls = (float*)smem;                         // [256][YSTR] (phase B)

  // ---- issue x loads (coalesced: 4 complete 256B row windows / instr) ----
  f32x4 xv[8];
#pragma unroll
  for (int p = 0; p < 8; ++p) {
    const int row = wid * 32 + p * 4 + rq;
    xv[p] = *(const f32x4*)(x + (size_t)(b0 + row) * ROWLEN + dbase + c4 * 4);
  }

  // ---- issue W loads (same coalesced mapping; L2-hot; 2 instrs/wave) ----
  f32x4 wv[2];
#pragma unroll
  for (int p = 0; p < 2; ++p) {
    const int o = wid * 8 + p * 4 + rq;
    wv[p] = *(const f32x4*)(W + (size_t)(dbase + o) * ROWLEN + dbase + c4 * 4);
  }

  // ---- stage to LDS (bf16) ----
#pragma unroll
  for (int p = 0; p < 8; ++p) {
    const int row = wid * 32 + p * 4 + rq;
    *(bf16x4*)(&xls[row * XSTR + c4 * 4]) = cvt4(xv[p]);
  }
#pragma unroll
  for (int p = 0; p < 2; ++p) {
    const int o = wid * 8 + p * 4 + rq;
    *(bf16x4*)(&wls[o * WSTR + c4 * 4]) = cvt4(wv[p]);
  }

  __syncthreads();   // barrier 1: tiles staged

  // ---- fragment reads (ALL LDS reads happen before barrier 2) ----
  bf16x8 wfrag[4][2];
#pragma unroll
  for (int g = 0; g < 4; ++g)
#pragma unroll
    for (int kh = 0; kh < 2; ++kh)
      wfrag[g][kh] = *(const bf16x8*)(&wls[(g * 16 + m16) * WSTR + kh * 32 + kg * 8]);

  bf16x8 afrag[2][2];   // [s][kh]; wave owns rows [wid*32, wid*32+32)
#pragma unroll
  for (int s = 0; s < 2; ++s) {
    const int rbase = wid * 32 + s * 16;
    afrag[s][0] = *(const bf16x8*)(&xls[(rbase + m16) * XSTR + kg * 8]);
    afrag[s][1] = *(const bf16x8*)(&xls[(rbase + m16) * XSTR + 32 + kg * 8]);
  }

  __syncthreads();   // barrier 2: safe to overlay y onto x/W region

  // ---- MFMA + scatter accs to LDS y-tile (wave-private rows) ----
  // Swapped-operand MFMA (r3-verified): D = W_tile . x_tile^T.
#pragma unroll
  for (int s = 0; s < 2; ++s) {
    const int rbase = wid * 32 + s * 16;
#pragma unroll
    for (int g = 0; g < 4; ++g) {
      f32x4 acc = (f32x4){0.f, 0.f, 0.f, 0.f};
      acc = __builtin_amdgcn_mfma_f32_16x16x32_bf16(wfrag[g][0], afrag[s][0], acc, 0, 0, 0);
      acc = __builtin_amdgcn_mfma_f32_16x16x32_bf16(wfrag[g][1], afrag[s][1], acc, 0, 0, 0);
      *(f32x4*)(&yls[(rbase + m16) * YSTR + g * 16 + kg * 4]) = acc;
    }
  }

  // Wave-private region: our ds_writes retired before our ds_reads issue.
  asm volatile("s_waitcnt lgkmcnt(0)" ::: "memory");
  __builtin_amdgcn_sched_barrier(0);

  // ---- coalesced NONTEMPORAL y store: 16-lane group = one full 256B window ----
#pragma unroll
  for (int p = 0; p < 8; ++p) {
    const int row = wid * 32 + p * 4 + rq;
    f32x4 v = *(const f32x4*)(&yls[row * YSTR + c4 * 4]);
    __builtin_nontemporal_store(v,
        (f32x4*)(y + (size_t)(b0 + row) * ROWLEN + dbase + c4 * 4));
  }
}

extern "C" void kernel_launch(void* const* d_in, const int* in_sizes, int n_in,
                              void* d_out, int out_size, void* d_ws, size_t ws_size,
                              hipStream_t stream) {
  const float* x = (const float*)d_in[0];
  const float* W = (const float*)d_in[1];
  float* y = (float*)d_out;
  const int B = in_sizes[0] / ROWLEN;   // 8192
  dim3 grid(B / TILE_B, NDET);
  ensemble_linear_v13<<<grid, dim3(THREADS), 0, stream>>>(x, W, y);
}